// Round 12
// baseline (302.590 us; speedup 1.0000x reference)
//
#include <hip/hip_runtime.h>

#define IH 256
#define IW 256
#define NRINGS 16
#define NBINS (NRINGS * 3 * 256)          // 12288 u32 = 48 KiB per hist
#define LUT_WORDS (IH * IW / 4)           // 16384 u32 = 64 KB
#define LUT_BYTES ((size_t)LUT_WORDS * 4)
#define PART_BYTES ((size_t)512 * NBINS * 4)   // 24.1 MB

// ---------- ring LUT (u8 per pixel, 255 = outside circle / center) ----------
__global__ __launch_bounds__(256)
void k_ringlut(unsigned int* __restrict__ lut) {
    const int gid = blockIdx.x * 256 + threadIdx.x;   // 0..16383
    const int y   = gid >> 6;
    const int x0  = (gid & 63) * 4;
    const int dy  = y - 128;
    const int dy2 = dy * dy;
    unsigned int w = 0;
    #pragma unroll
    for (int j = 0; j < 4; ++j) {
        const int dx = x0 + j - 128;
        const int d2 = dy2 + dx * dx;
        unsigned int r;
        if (d2 == 0 || d2 > 16384) r = 255u;
        else {
            // ring = ceil(sqrt(d2)/8) - 1, exact (float sqrt + integer correction)
            int kk = (int)ceilf(sqrtf((float)d2) * 0.125f);
            if (64 * kk * kk < d2) kk++;
            else if (kk > 1 && 64 * (kk - 1) * (kk - 1) >= d2) kk--;
            r = (unsigned)(kk - 1);                   // 0..15
        }
        w |= r << (8 * j);
    }
    lut[gid] = w;
}

// ---------- K1: half-image per block, LDS u32 hist, dump to d_ws ----------
// grid (256 batches, 2 halves) x 1024 threads. Wave w covers full rows
// half*128 + w + 16k (k=0..7), 64 lanes x float4. Loads are UNCONDITIONAL and
// fully unrolled so the compiler can pipeline them (ring==255 skips hist only).
__global__ __launch_bounds__(1024)
void k1_hist(const float* __restrict__ img,
             const unsigned int* __restrict__ lut,
             unsigned int* __restrict__ parts) {
    const int b    = blockIdx.x;
    const int half = blockIdx.y;
    const int tid  = threadIdx.x;

    __shared__ __align__(16) unsigned int hist[NBINS];   // 48 KiB

    for (int i = tid; i < NBINS; i += 1024) hist[i] = 0u;
    __syncthreads();

    const int xg = (tid & 63) * 4;
    const int wv = tid >> 6;                 // 0..15
    const int y0 = (half << 7) + wv;         // first row for this thread
    const float* base = img + (size_t)b * 3 * IH * IW;
    const int lc = xg >> 2;

    unsigned int rw[8];
    #pragma unroll
    for (int k = 0; k < 8; ++k) rw[k] = lut[((y0 + (k << 4)) << 6) + lc];

    #pragma unroll
    for (int k = 0; k < 8; ++k) {
        const int off = (y0 + (k << 4)) * IW + xg;
        const float4 f0 = *(const float4*)(base + off);
        const float4 f1 = *(const float4*)(base + IH * IW + off);
        const float4 f2 = *(const float4*)(base + 2 * IH * IW + off);
        const float va[3][4] = {{f0.x, f0.y, f0.z, f0.w},
                                {f1.x, f1.y, f1.z, f1.w},
                                {f2.x, f2.y, f2.z, f2.w}};
        #pragma unroll
        for (int j = 0; j < 4; ++j) {
            const unsigned int ring = (rw[k] >> (8 * j)) & 255u;
            if (ring == 255u) continue;      // outside circle or center px
            unsigned int* hb = &hist[(ring * 3) << 8];
            #pragma unroll
            for (int c = 0; c < 3; ++c) {
                // exact quantize; value in [127,254] for input in [0,1) -> no clamp
                const int iv = (int)floorf((va[c][j] * 0.5f + 0.5f) * 255.0f);
                atomicAdd(&hb[(c << 8) + iv], 1u);
            }
        }
    }

    __syncthreads();
    // coalesced uint4 dump of the partial hist
    uint4* dst = (uint4*)(parts + ((size_t)((b << 1) + half)) * NBINS);
    const uint4* src = (const uint4*)hist;
    #pragma unroll
    for (int i = tid; i < NBINS / 4; i += 1024) dst[i] = src[i];
}

// ---------- K2: sum the two halves, compute stats ----------
__global__ __launch_bounds__(1024)
void k2_stats(const unsigned int* __restrict__ parts, float* __restrict__ out) {
    const int b   = blockIdx.x;
    const int tid = threadIdx.x;

    __shared__ __align__(16) unsigned int hist[NBINS];

    const uint4* p0 = (const uint4*)(parts + ((size_t)(b << 1)) * NBINS);
    const uint4* p1 = (const uint4*)(parts + ((size_t)((b << 1) + 1)) * NBINS);
    uint4* s = (uint4*)hist;
    for (int i = tid; i < NBINS / 4; i += 1024) {
        const uint4 a = p0[i], c = p1[i];
        s[i] = make_uint4(a.x + c.x, a.y + c.y, a.z + c.z, a.w + c.w);
    }
    __syncthreads();

    if (tid < NRINGS * 3) {
        const int ring = tid / 3;
        const int c    = tid - ring * 3;
        const unsigned int* h = &hist[tid << 8];

        unsigned int n = 0, sum = 0, sumsq = 0;
        #pragma unroll 8
        for (int v = 0; v < 256; ++v) {
            const unsigned int cnt = h[v];
            n     += cnt;
            sum   += cnt * (unsigned)v;
            sumsq += cnt * (unsigned)(v * v);
        }

        const double dn   = (double)n;
        const double mean = (double)sum / dn;
        double var = (double)sumsq / dn - mean * mean;
        if (var < 0.0) var = 0.0;

        const unsigned int j1 = (n - 1u) >> 1;
        const unsigned int j2 = n >> 1;
        unsigned int cum = 0;
        int v1i = -1, v2i = -1;
        for (int v = 0; v < 256; ++v) {
            cum += h[v];
            if (v1i < 0 && cum > j1) v1i = v;
            if (cum > j2) { v2i = v; break; }
        }

        float* o = out + ((size_t)b * NRINGS + ring) * 9;
        o[c]     = (float)mean;
        o[3 + c] = (float)sqrt(var);
        o[6 + c] = 0.5f * (float)(v1i + v2i);
    }
}

// ---------- fallback (round-10 fused, needs only the 64 KB LUT) ----------
__global__ __launch_bounds__(1024)
void radial_fused(const float* __restrict__ img,
                  const unsigned int* __restrict__ lut,
                  float* __restrict__ out) {
    const int b   = blockIdx.x;
    const int tid = threadIdx.x;
    __shared__ unsigned int hist[NBINS];
    for (int i = tid; i < NBINS; i += 1024) hist[i] = 0u;
    __syncthreads();
    const int xg = (tid & 63) * 4;
    const int r0 = tid >> 6;
    const float* base = img + (size_t)b * 3 * IH * IW;
    const int lc = xg >> 2;
    unsigned int rw[16];
    #pragma unroll
    for (int k = 0; k < 16; ++k) rw[k] = lut[((r0 + (k << 4)) << 6) + lc];
    #pragma unroll
    for (int k = 0; k < 16; ++k) {
        const int off = (r0 + (k << 4)) * IW + xg;
        const float4 f0 = *(const float4*)(base + off);
        const float4 f1 = *(const float4*)(base + IH * IW + off);
        const float4 f2 = *(const float4*)(base + 2 * IH * IW + off);
        const float va[3][4] = {{f0.x, f0.y, f0.z, f0.w},
                                {f1.x, f1.y, f1.z, f1.w},
                                {f2.x, f2.y, f2.z, f2.w}};
        #pragma unroll
        for (int j = 0; j < 4; ++j) {
            const unsigned int ring = (rw[k] >> (8 * j)) & 255u;
            if (ring == 255u) continue;
            unsigned int* hb = &hist[(ring * 3) << 8];
            #pragma unroll
            for (int c = 0; c < 3; ++c) {
                const int iv = (int)floorf((va[c][j] * 0.5f + 0.5f) * 255.0f);
                atomicAdd(&hb[(c << 8) + iv], 1u);
            }
        }
    }
    __syncthreads();
    if (tid < NRINGS * 3) {
        const int ring = tid / 3;
        const int c    = tid - ring * 3;
        const unsigned int* h = &hist[tid << 8];
        unsigned int n = 0, sum = 0, sumsq = 0;
        for (int v = 0; v < 256; ++v) {
            const unsigned int cnt = h[v];
            n += cnt; sum += cnt * (unsigned)v; sumsq += cnt * (unsigned)(v * v);
        }
        const double dn = (double)n;
        const double mean = (double)sum / dn;
        double var = (double)sumsq / dn - mean * mean;
        if (var < 0.0) var = 0.0;
        const unsigned int j1 = (n - 1u) >> 1, j2 = n >> 1;
        unsigned int cum = 0; int v1i = -1, v2i = -1;
        for (int v = 0; v < 256; ++v) {
            cum += h[v];
            if (v1i < 0 && cum > j1) v1i = v;
            if (cum > j2) { v2i = v; break; }
        }
        float* o = out + ((size_t)b * NRINGS + ring) * 9;
        o[c] = (float)mean; o[3 + c] = (float)sqrt(var);
        o[6 + c] = 0.5f * (float)(v1i + v2i);
    }
}

extern "C" void kernel_launch(void* const* d_in, const int* in_sizes, int n_in,
                              void* d_out, int out_size, void* d_ws, size_t ws_size,
                              hipStream_t stream) {
    const float* img = (const float*)d_in[0];
    float* out = (float*)d_out;
    unsigned int* lut = (unsigned int*)d_ws;                 // 64 KB
    k_ringlut<<<LUT_WORDS / 256, 256, 0, stream>>>(lut);
    if (ws_size >= LUT_BYTES + PART_BYTES) {
        unsigned int* parts = (unsigned int*)((char*)d_ws + LUT_BYTES);
        k1_hist<<<dim3(256, 2), 1024, 0, stream>>>(img, lut, parts);
        k2_stats<<<256, 1024, 0, stream>>>(parts, out);
    } else {
        radial_fused<<<256, 1024, 0, stream>>>(img, lut, out);
    }
}